// Round 25
// baseline (200.209 us; speedup 1.0000x reference)
//
#include <hip/hip_runtime.h>
#include <hip/hip_bf16.h>
#include <math.h>

#define S_LEN 3072
#define DMODEL 1536
#define NQKV 4608
#define NHEAD 12
#define HDIM 128
#define NSPLIT 4   // max planes in Opart; per-tg split counts are {2,3,4,3}

typedef __attribute__((ext_vector_type(8))) short bf16x8;
typedef __attribute__((ext_vector_type(4))) float f32x4;
typedef __attribute__((ext_vector_type(4))) unsigned int u32x4;

__device__ __forceinline__ void gload_lds16(const void* g, void* lds) {
  __builtin_amdgcn_global_load_lds(
      (const __attribute__((address_space(1))) unsigned int*)g,
      (__attribute__((address_space(3))) unsigned int*)lds, 16, 0, 0);
}

// partitioned index p -> original sequence index s
__device__ __forceinline__ int invperm(int p) {
  int blk = p >> 7;
  int w   = p & 127;
  int fb  = blk / 6;
  int rem = blk - fb * 6;
  int hb  = rem / 3;
  int wb  = rem - hb * 3;
  int fi  = fb * 8 + (w >> 4);
  int hi  = hb * 4 + ((w >> 2) & 3);
  int wi  = wb * 4 + (w & 3);
  return (fi * 8 + hi) * 12 + wi;
}

// original sequence index s -> partitioned index p
__device__ __forceinline__ int fwdperm(int s) {
  int fi = s / 96;
  int rem = s - fi * 96;
  int hi = rem / 12;
  int wi = rem - hi * 12;
  int fb = fi >> 3, wf = fi & 7;
  int hb = hi >> 2, wh = hi & 3;
  int wb = wi >> 2, ww = wi & 3;
  return ((fb * 2 + hb) * 3 + wb) * 128 + wf * 16 + wh * 4 + ww;
}

__device__ __forceinline__ void store_out(float* p, float v) { *p = v; }
__device__ __forceinline__ void store_out(__hip_bfloat16* p, float v) { *p = __float2bfloat16(v); }

// ---------------------------------------------------------------------------
// Fused prep: blocks [0,4626): x fp32->bf16 convert + bias concat;
// blocks [4626,6930): the 4 weight transposes (fp32 -> bf16 transposed).
// ---------------------------------------------------------------------------
__global__ __launch_bounds__(256) void prep_all(
    const float* __restrict__ in, __hip_bfloat16* __restrict__ out,
    const float* __restrict__ bq, const float* __restrict__ bk,
    const float* __restrict__ bv, float* __restrict__ bqkv,
    const float* __restrict__ W0, const float* __restrict__ W1,
    const float* __restrict__ W2, const float* __restrict__ W3,
    __hip_bfloat16* __restrict__ Wtqkv, __hip_bfloat16* __restrict__ Wot)
{
  __shared__ __hip_bfloat16 Ls[64][67];
  const int bid = blockIdx.x, t = threadIdx.x;
  if (bid < 4608) {
    int i = bid * 256 + t;
    float4 v = ((const float4*)in)[i];
    __hip_bfloat16 b[4] = {__float2bfloat16(v.x), __float2bfloat16(v.y),
                           __float2bfloat16(v.z), __float2bfloat16(v.w)};
    ((ushort4*)out)[i] = *(ushort4*)b;
    return;
  }
  if (bid < 4626) {
    int j = (bid - 4608) * 256 + t;   // 0..4607
    float v = (j < 1536) ? bq[j] : (j < 3072) ? bk[j - 1536] : bv[j - 3072];
    bqkv[j] = v;
    return;
  }
  // weight transposes
  const int idx = bid - 4626;         // 0..2303
  const int z = idx / 576;
  const int rem = idx - z * 576;
  const int r0 = (rem / 24) * 64, c0 = (rem % 24) * 64;
  const float* W = (z == 0) ? W0 : (z == 1) ? W1 : (z == 2) ? W2 : W3;
  __hip_bfloat16* Wt = (z < 3) ? Wtqkv + (size_t)z * DMODEL * DMODEL : Wot;
  {
    int rr = t >> 2, cb = (t & 3) * 16;
    const float4* src = (const float4*)(W + (size_t)(r0 + rr) * DMODEL + c0 + cb);
    #pragma unroll
    for (int i = 0; i < 4; ++i) {
      float4 v = src[i];
      Ls[rr][cb + i * 4 + 0] = __float2bfloat16(v.x);
      Ls[rr][cb + i * 4 + 1] = __float2bfloat16(v.y);
      Ls[rr][cb + i * 4 + 2] = __float2bfloat16(v.z);
      Ls[rr][cb + i * 4 + 3] = __float2bfloat16(v.w);
    }
  }
  __syncthreads();
  {
    int cc = t >> 2, rb = (t & 3) * 16;
    unsigned short tmp[16];
    #pragma unroll
    for (int i = 0; i < 16; ++i) tmp[i] = *(unsigned short*)&Ls[rb + i][cc];
    uint4* dst = (uint4*)(Wt + (size_t)(c0 + cc) * DMODEL + r0 + rb);
    dst[0] = ((uint4*)tmp)[0];
    dst[1] = ((uint4*)tmp)[1];
  }
}

// ---------------------------------------------------------------------------
// bf16 MFMA GEMM, 128xBN tile, BK=128 (halves barrier/stage events vs BK=64,
// the proven dominant lever per R19).  Single-buffered 48KB LDS (3 blk/CU;
// R16->R17 showed this GEMM is insensitive to block-TLP above ~3/CU).
// XOR-swizzled tiles: pre-swizzled global source + same XOR on reads
// (row stride 256B; (row&7)<<4 spans all 8 bank granules).  2D XCD patch
// swizzle.  K accumulation order identical to BK=64 -> bit-identical output.
// ---------------------------------------------------------------------------
template <typename OutT, int BN>
__global__ __launch_bounds__(256) void gemm_bt(
    const __hip_bfloat16* __restrict__ A, const __hip_bfloat16* __restrict__ Bt,
    const float* __restrict__ bias, OutT* __restrict__ C, int M, int N, int K)
{
  constexpr int NB = BN / 32;                 // B fragments per wave
  __shared__ __hip_bfloat16 As[128 * 128];
  __shared__ __hip_bfloat16 Bs[BN * 128];
  const int tid = threadIdx.x, lane = tid & 63, wid = tid >> 6;
  const int l15 = lane & 15, l4 = lane >> 4;
  // 2D XCD patch swizzle (bijective): xcd = lin&7 -> (col-chunk, row-chunk)
  const int lin = blockIdx.y * gridDim.x + blockIdx.x;
  const int xcd = lin & 7, idx = lin >> 3;
  const int CX = gridDim.x >> 2, CY = gridDim.y >> 1;
  const int cx = xcd & 3, cy = xcd >> 2;
  const int lc = idx % CX, lr = idx / CX;
  const int row0 = (cy * CY + lr) * 128, col0 = (cx * CX + lc) * BN;
  const int wr = (wid >> 1) * 64, wc = (wid & 1) * (BN / 2);

  f32x4 acc[4][NB] = {};
  const char* Ab = (const char*)A;
  const char* Bb = (const char*)Bt;

  auto STAGE = [&](int k0) {
    // A tile: 128 rows x 256B = 2048 16B-slots, 8 per thread
    #pragma unroll
    for (int i = 0; i < 8; ++i) {
      int slot = i * 256 + tid;
      int r = slot >> 4;
      int b = ((slot & 15) * 16) ^ ((r & 7) << 4);   // pre-swizzled source
      gload_lds16(Ab + ((size_t)(row0 + r) * K + k0) * 2 + b,
                  (char*)As + slot * 16);
    }
    // B tile: BN rows x 256B, BN/16 slots per thread
    #pragma unroll
    for (int i = 0; i < BN / 16; ++i) {
      int slot = i * 256 + tid;
      int r = slot >> 4;
      int b = ((slot & 15) * 16) ^ ((r & 7) << 4);
      gload_lds16(Bb + ((size_t)(col0 + r) * K + k0) * 2 + b,
                  (char*)Bs + slot * 16);
    }
  };

  for (int k0 = 0; k0 < K; k0 += 128) {
    STAGE(k0);
    __syncthreads();              // vmcnt drain; staged tile visible
    #pragma unroll
    for (int kk = 0; kk < 4; ++kk) {
      bf16x8 a[4], b[NB];
      #pragma unroll
      for (int m = 0; m < 4; ++m) {
        int row = wr + m * 16 + l15;
        int byte = (kk * 64 + l4 * 16) ^ ((row & 7) << 4);
        a[m] = *(const bf16x8*)((const char*)As + row * 256 + byte);
      }
      #pragma unroll
      for (int n = 0; n < NB; ++n) {
        int row = wc + n * 16 + l15;
        int byte = (kk * 64 + l4 * 16) ^ ((row & 7) << 4);
        b[n] = *(const bf16x8*)((const char*)Bs + row * 256 + byte);
      }
      #pragma unroll
      for (int m = 0; m < 4; ++m)
        #pragma unroll
        for (int n = 0; n < NB; ++n)
          acc[m][n] = __builtin_amdgcn_mfma_f32_16x16x32_bf16(a[m], b[n], acc[m][n], 0, 0, 0);
    }
    __syncthreads();              // compute done -> safe to overwrite LDS
  }

  #pragma unroll
  for (int m = 0; m < 4; ++m) {
    #pragma unroll
    for (int r = 0; r < 4; ++r) {
      size_t row = row0 + wr + m * 16 + l4 * 4 + r;
      #pragma unroll
      for (int n = 0; n < NB; ++n) {
        int col = col0 + wc + n * 16 + l15;
        store_out(&C[row * N + col], acc[m][n][r] + bias[col]);
      }
    }
  }
}

// ---------------------------------------------------------------------------
// Fused mid: blocks [0,6144): RMSNorm+RoPE for Q (bid&1==0) / K (bid&1==1),
// permuted head-blocked bf16 out (Q pre-scaled into log2 domain);
// blocks [6144,6720): V -> transposed+permuted Vt[h][d][p].
// ---------------------------------------------------------------------------
__global__ __launch_bounds__(256) void mid_all(
    const __hip_bfloat16* __restrict__ X,
    const float* __restrict__ gq, const float* __restrict__ gk,
    const float* __restrict__ freqs,
    __hip_bfloat16* __restrict__ OutQ, __hip_bfloat16* __restrict__ OutK,
    __hip_bfloat16* __restrict__ Vt)
{
  __shared__ __hip_bfloat16 Ls[64][136];
  __shared__ float wsum[4];
  const int bid = blockIdx.x, tid = threadIdx.x;
  if (bid < 6144) {
    const int s = bid >> 1, sec = bid & 1;
    const float* g = sec ? gk : gq;
    __hip_bfloat16* Out = sec ? OutK : OutQ;
    const float qsc = sec ? 1.0f : (0.08838834764831843f * 1.4426950408889634f);
    const unsigned int* row = (const unsigned int*)(X + (size_t)s * NQKV + sec * 1536);
    float e0[3], e1[3];
    float ss = 0.f;
    #pragma unroll
    for (int i = 0; i < 3; ++i) {
      unsigned int u = row[tid + i * 256];
      float a = __uint_as_float(u << 16);
      float b = __uint_as_float(u & 0xffff0000u);
      e0[i] = a; e1[i] = b;
      ss += a * a + b * b;
    }
    #pragma unroll
    for (int off = 32; off > 0; off >>= 1) ss += __shfl_down(ss, off, 64);
    if ((tid & 63) == 0) wsum[tid >> 6] = ss;
    __syncthreads();
    float rs = rsqrtf((wsum[0] + wsum[1] + wsum[2] + wsum[3]) * (1.f / DMODEL) + 1e-5f);
    rs *= qsc;
    const int p = fwdperm(s);
    #pragma unroll
    for (int i = 0; i < 3; ++i) {
      int pi = tid + i * 256;             // pair index 0..767
      int n = pi >> 6, d2 = pi & 63;
      float c  = freqs[(size_t)s * 128 + 2 * d2];
      float sn = freqs[(size_t)s * 128 + 2 * d2 + 1];
      float y0 = e0[i] * rs * g[2 * pi];
      float y1 = e1[i] * rs * g[2 * pi + 1];
      float o0 = y0 * c - y1 * sn;
      float o1 = y0 * sn + y1 * c;
      __hip_bfloat16 b0 = __float2bfloat16(o0), b1 = __float2bfloat16(o1);
      unsigned int u = ((unsigned int)(*(unsigned short*)&b1) << 16) | (*(unsigned short*)&b0);
      ((unsigned int*)Out)[(((size_t)n * S_LEN + p) * HDIM + 2 * d2) >> 1] = u;
    }
    return;
  }
  // V transpose: idx 0..575 -> (p0, h)
  const int idx = bid - 6144;
  const int p0 = (idx % 48) * 64, h = idx / 48;
  const __hip_bfloat16* Vsec = X + 3072;    // V section of QKVbf
  {
    int pl = tid & 63, dg = tid >> 6;
    int sidx = invperm(p0 + pl);
    const uint4* src = (const uint4*)(Vsec + (size_t)sidx * NQKV + h * HDIM + dg * 32);
    #pragma unroll
    for (int i = 0; i < 4; ++i) {
      uint4 v = src[i];
      *(uint4*)&Ls[pl][dg * 32 + i * 8] = v;
    }
  }
  __syncthreads();
  {
    int d = tid >> 1, ph = tid & 1;
    unsigned short tmp[32];
    #pragma unroll
    for (int i = 0; i < 32; ++i) tmp[i] = *(unsigned short*)&Ls[ph * 32 + i][d];
    uint4* dst = (uint4*)(Vt + ((size_t)h * HDIM + d) * S_LEN + p0 + ph * 32);
    #pragma unroll
    for (int i = 0; i < 4; ++i) dst[i] = ((uint4*)tmp)[i];
  }
}

// ---------------------------------------------------------------------------
// MFMA flash attention (R23: swapped QK^T, register-resident P, sigma
// K-swizzle, balanced per-tg key-splits {2,3,4,3}, setprio, hoisted LDS
// bases, T4 double-buffer with counted vmcnt + raw s_barrier).
// ---------------------------------------------------------------------------
__global__ __launch_bounds__(512) void attn_mfma(
    const __hip_bfloat16* __restrict__ Qp, const __hip_bfloat16* __restrict__ Kp,
    const __hip_bfloat16* __restrict__ Vt,
    __hip_bfloat16* __restrict__ Opart, float* __restrict__ ml)
{
  __shared__ __hip_bfloat16 Ks[2][64 * 128];              // [key][d], sigma-swizzled
  __shared__ __hip_bfloat16 Vs[2][64 * 128];              // [d][key], swizzled

  // ---- XCD-locality remap: 864 blocks, 108 per XCD ----
  const int hw = blockIdx.x;                 // 0..863
  const int L  = (hw & 7) * 108 + (hw >> 3);
  const int j  = L % 6;
  const int c  = (L / 6) % 12;               // (tg,split) combo
  const int h  = L / 72;
  int tg, split;
  if (c < 2)      { tg = 0; split = c; }
  else if (c < 5) { tg = 1; split = c - 2; }
  else if (c < 9) { tg = 2; split = c - 5; }
  else            { tg = 3; split = c - 9; }
  const int qb = tg * 6 + j;

  const int tid = threadIdx.x, lane = tid & 63, wid = tid >> 6;
  const int l15 = lane & 15, l4 = lane >> 4;

  const int cbegin = split * 12, cend = cbegin + 12;   // 12 chunks per block

  const char* Kh = (const char*)(Kp + (size_t)h * S_LEN * HDIM);
  const char* Vh = (const char*)(Vt + (size_t)h * HDIM * S_LEN);

  // gathered key row base for QK^T A-operand
  const int kbase = 8 * (l15 >> 2) + (l15 & 3);
  // sigma(key)<<4 is ct-independent: sigma = (l15&3) | (((l15>>2)&1)<<2)
  const int ksw = (((l15 & 3) | (((l15 >> 2) & 1) << 2))) << 4;

  // loop-invariant LDS read base pointers (buffer 0; buffer 1 = +16384 B)
  const char* kbp[4];
  #pragma unroll
  for (int dc = 0; dc < 4; ++dc)
    kbp[dc] = (const char*)Ks[0] + kbase * 256 + ((dc * 64 + l4 * 16) ^ ksw);
  const char* vbp[2];
  #pragma unroll
  for (int ks = 0; ks < 2; ++ks)
    vbp[ks] = (const char*)Vs[0] + l15 * 128 + ((ks * 64 + l4 * 16) ^ ((l15 & 7) << 4));

  // hoisted 32-bit staging offsets (K uses sigma; V uses (row&7))
  unsigned int koffA, voffA;
  {
    unsigned int kr = tid >> 4;
    unsigned int sig = (kr & 3) | (((kr >> 3) & 1) << 2);
    koffA = kr * 256 + (((tid & 15) * 16) ^ (sig << 4));
    unsigned int vr = tid >> 3;
    voffA = vr * (S_LEN * 2) + (((tid & 7) * 16) ^ ((vr & 7) << 4));
  }

  auto k0_of = [&](int ci) { return ci * 64 + ((tg == 3 && ci >= 12) ? 768 : 0); };
  auto STAGE = [&](int buf, int k0) {
    const char* ks = Kh + (size_t)k0 * 256;
    char* kd = (char*)Ks[buf];
    gload_lds16(ks + koffA,        kd + tid * 16);
    gload_lds16(ks + koffA + 8192, kd + tid * 16 + 8192);   // row+32: sigma invariant
    const char* vs = Vh + (size_t)k0 * 2 + voffA;
    char* vd = (char*)Vs[buf];
    gload_lds16(vs,                          vd + tid * 16);
    gload_lds16(vs + (size_t)64 * S_LEN * 2, vd + tid * 16 + 8192);
  };

  // Q fragments in registers (pre-scaled; serve as MFMA B-operand)
  bf16x8 aq[4];
  {
    const __hip_bfloat16* qr = Qp + (size_t)h * S_LEN * HDIM
        + (size_t)(qb * 128 + wid * 16 + l15) * HDIM + l4 * 8;
    #pragma unroll
    for (int dc = 0; dc < 4; ++dc) aq[dc] = *(const bf16x8*)(qr + dc * 32);
  }

  f32x4 oacc[8] = {};
  float m2 = -1e30f;     // running max for this lane's q (=l15)
  float lsum = 0.f;      // per-lane partial (its 16 keys per chunk)

  // prologue: stage first chunk into buffer 0
  STAGE(0, k0_of(cbegin));
  int cur = 0;

  for (int ci = cbegin; ci < cend; ++ci) {
    if (ci + 1 < cend) {
      STAGE(cur ^ 1, k0_of(ci + 1));
      // wait only cur's 4 loads (issued last iteration / prologue);
      // the 4 just-issued prefetch loads stay in flight across the barrier
      asm volatile("s_waitcnt vmcnt(4)" ::: "memory");
    } else {
      asm volatile("s_waitcnt vmcnt(0)" ::: "memory");
    }
    __builtin_amdgcn_s_barrier();     // cur's staged K/V visible to all waves
    __builtin_amdgcn_sched_barrier(0);

    const int bufoff = cur << 14;     // byte offset to current buffer

    // swapped QK^T: sfr[ct] = S^T for gathered keys, q = l15
    f32x4 sfr[4] = {};
    __builtin_amdgcn_s_setprio(1);
    #pragma unroll
    for (int ct = 0; ct < 4; ++ct) {
      const int cto = ((ct >> 1) * 32 + (ct & 1) * 4) * 256;   // 0,1024,8192,9216
      #pragma unroll
      for (int dc = 0; dc < 4; ++dc) {
        bf16x8 kf = *(const bf16x8*)(kbp[dc] + bufoff + cto);
        sfr[ct] = __builtin_amdgcn_mfma_f32_16x16x32_bf16(kf, aq[dc], sfr[ct], 0, 0, 0);
      }
    }
    __builtin_amdgcn_s_setprio(0);
    // defer-max online softmax (per-lane partial max over 16 values)
    float lmax = fmaxf(
        fmaxf(fmaxf(sfr[0][0], sfr[0][1]), fmaxf(sfr[0][2], sfr[0][3])),
        fmaxf(fmaxf(fmaxf(sfr[1][0], sfr[1][1]), fmaxf(sfr[1][2], sfr[1][3])),
              fmaxf(fmaxf(fmaxf(sfr[2][0], sfr[2][1]), fmaxf(sfr[2][2], sfr[2][3])),
                    fmaxf(fmaxf(sfr[3][0], sfr[3][1]), fmaxf(sfr[3][2], sfr[3][3])))));
    bool grow = lmax > m2 + 8.f;
    if (ci == cbegin || __any(grow)) {
      float mf = lmax;
      mf = fmaxf(mf, __shfl_xor(mf, 16, 64));
      mf = fmaxf(mf, __shfl_xor(mf, 32, 64));
      float mn = fmaxf(m2, mf);
      float corr = exp2f(m2 - mn);
      m2 = mn;
      lsum *= corr;
      float cr[4];
      #pragma unroll
      for (int r = 0; r < 4; ++r) cr[r] = __shfl(corr, l4 * 4 + r, 64);
      #pragma unroll
      for (int n = 0; n < 8; ++n)
        #pragma unroll
        for (int r = 0; r < 4; ++r) oacc[n][r] *= cr[r];
    }
    // P = exp2(S - m) in place; accumulate per-lane row-sum partial
    #pragma unroll
    for (int ct = 0; ct < 4; ++ct)
      #pragma unroll
      for (int r = 0; r < 4; ++r) {
        float p = exp2f(sfr[ct][r] - m2);
        sfr[ct][r] = p;
        lsum += p;
      }
    // PV: A = P packed lane-locally (no LDS), B = V via base+immediate reads
    #pragma unroll
    for (int ks = 0; ks < 2; ++ks) {
      u32x4 wv;
      {
        __hip_bfloat16 a0 = __float2bfloat16(sfr[2 * ks][0]);
        __hip_bfloat16 a1 = __float2bfloat16(sfr[2 * ks][1]);
        __hip_bfloat16 a2 = __float2bfloat16(sfr[2 * ks][2]);
        __hip_bfloat16 a3 = __float2bfloat16(sfr[2 * ks][3]);
        __hip_bfloat16 b0 = __float2bfloat16(sfr[2 * ks + 1][0]);
        __hip_bfloat16 b1 = __float2bfloat16(sfr[2 * ks + 1][1]);
        __hip_bfloat16 b2 = __float2bfloat16(sfr[2 * ks + 1][2]);
        __hip_bfloat16 b3 = __float2bfloat16(sfr[2 * ks + 1][3]);
        wv[0] = ((unsigned int)(*(unsigned short*)&a1) << 16) | (*(unsigned short*)&a0);
        wv[1] = ((unsigned int)(*(unsigned short*)&a3) << 16) | (*(unsigned short*)&a2);
        wv[2] = ((unsigned int)(*(unsigned short*)&b1) << 16) | (*(unsigned short*)&b0);
        wv[3] = ((unsigned int)(*(unsigned short*)&b3) << 16) | (*(unsigned short*)&b2);
      }
      bf16x8 pa = __builtin_bit_cast(bf16x8, wv);
      __builtin_amdgcn_s_setprio(1);
      #pragma unroll
      for (int n = 0; n < 8; ++n) {
        bf16x8 bv = *(const bf16x8*)(vbp[ks] + bufoff + n * 2048);
        oacc[n] = __builtin_amdgcn_mfma_f32_16x16x32_bf16(pa, bv, oacc[n], 0, 0, 0);
      }
      __builtin_amdgcn_s_setprio(0);
    }
    __builtin_amdgcn_sched_barrier(0);
    __builtin_amdgcn_s_barrier();   // all waves done reading cur -> reusable
    cur ^= 1;
  }

  // epilogue: full row-sum per q (=l15) via 2 shuffles; normalize & write
  float t = lsum;
  t += __shfl_xor(t, 16, 64);
  t += __shfl_xor(t, 32, 64);
  float inv = 1.0f / t;
  #pragma unroll
  for (int r = 0; r < 4; ++r) {
    float invr = __shfl(inv, l4 * 4 + r, 64);   // lane (l4*4+r) owns that q
    int qrow = qb * 128 + wid * 16 + l4 * 4 + r;
    size_t rowid = (size_t)(split * NHEAD + h) * S_LEN + qrow;
    __hip_bfloat16* dst = Opart + rowid * HDIM;
    #pragma unroll
    for (int n = 0; n < 8; ++n)
      dst[n * 16 + l15] = __float2bfloat16(oacc[n][r] * invr);
  }
  if (lane < 16) {
    int qrow = qb * 128 + wid * 16 + lane;
    size_t rowid = (size_t)(split * NHEAD + h) * S_LEN + qrow;
    ml[rowid * 2 + 0] = m2;
    ml[rowid * 2 + 1] = t;
  }
}

// ---------------------------------------------------------------------------
// Merge the key-split partials, fully unrolled over NSPLIT=4 with invalid
// planes masked (m=-1e30 -> weight exp2(-inf)*l=0; max unaffected).
// Per-tg valid plane counts: {2,3,4,3}.
// ---------------------------------------------------------------------------
__global__ __launch_bounds__(256) void attn_merge(
    const __hip_bfloat16* __restrict__ Opart, const float* __restrict__ ml,
    __hip_bfloat16* __restrict__ AO)
{
  const int rid = blockIdx.x * 4 + (threadIdx.x >> 6);
  const int lane = threadIdx.x & 63;
  const int h = rid / S_LEN, q = rid - h * S_LEN;
  const int tg = q / 768;
  const int nsp = (tg == 0) ? 2 : (tg == 2) ? 4 : 3;
  size_t rr[NSPLIT];
  float m[NSPLIT], l[NSPLIT];
  float mm = -1e30f;
  #pragma unroll
  for (int s = 0; s < NSPLIT; ++s) {
    rr[s] = (size_t)(s * NHEAD + h) * S_LEN + q;
    bool valid = (s < nsp);
    m[s] = valid ? ml[rr[s] * 2] : -1e30f;
    l[s] = valid ? ml[rr[s] * 2 + 1] : 0.f;
    mm = fmaxf(mm, m[s]);
  }
  float wsum = 0.f, wgt[NSPLIT];
  #pragma unroll
  for (int s = 0; s < NSPLIT; ++s) { wgt[s] = l[s] * exp2f(m[s] - mm); wsum += wgt[s]; }
  float inv = 1.0f / wsum;
  float o0 = 0.f, o1 = 0.f;
  #pragma unroll
  for (int s = 0; s < NSPLIT; ++s) {
    unsigned int u = ((const unsigned int*)(Opart + rr[s] * HDIM))[lane];
    float a = wgt[s] * inv;
    o0 += a * __uint_as_float(u << 16);
    o1 += a * __uint_as_float(u & 0xffff0000u);
  }
  __hip_bfloat16 b0 = __float2bfloat16(o0), b1 = __float2bfloat16(o1);
  unsigned int u = ((unsigned int)(*(unsigned short*)&b1) << 16) | (*(unsigned short*)&b0);
  int sorig = invperm(q);
  ((unsigned int*)(AO + (size_t)sorig * DMODEL + h * HDIM))[lane] = u;
}

// ---------------------------------------------------------------------------
extern "C" void kernel_launch(void* const* d_in, const int* in_sizes, int n_in,
                              void* d_out, int out_size, void* d_ws, size_t ws_size,
                              hipStream_t stream)
{
  (void)in_sizes; (void)n_in; (void)out_size; (void)ws_size;
  const float* x     = (const float*)d_in[0];
  const float* freqs = (const float*)d_in[1];
  const float* Wq    = (const float*)d_in[2];
  const float* bq    = (const float*)d_in[3];
  const float* Wk    = (const float*)d_in[4];
  const float* bk    = (const float*)d_in[5];
  const float* Wv    = (const float*)d_in[6];
  const float* bv    = (const float*)d_in[7];
  const float* Wo    = (const float*)d_in[8];
  const float* bo    = (const float*)d_in[9];
  const float* gq    = (const float*)d_in[10];
  const float* gk    = (const float*)d_in[11];
  float* out = (float*)d_out;

  // ws layout (Wot after AO so Opart can overlay Wtqkv+QKVbf):
  char* w = (char*)d_ws;
  __hip_bfloat16* xbf    = (__hip_bfloat16*)(w);               //  0        9,437,184
  __hip_bfloat16* Wtqkv  = (__hip_bfloat16*)(w + 9437184);     //          14,155,776
  __hip_bfloat16* QKVbf  = (__hip_bfloat16*)(w + 23592960);    //          28,311,552
  __hip_bfloat16* Qp     = (__hip_bfloat16*)(w + 51904512);    //           9,437,184
  __hip_bfloat16* Kp     = (__hip_bfloat16*)(w + 61341696);    //           9,437,184
  __hip_bfloat16* Vtb    = (__hip_bfloat16*)(w + 70778880);    //           9,437,184
  __hip_bfloat16* AO     = (__hip_bfloat16*)(w + 80216064);    //           9,437,184
  __hip_bfloat16* Wot    = (__hip_bfloat16*)(w + 89653248);    //           4,718,592
  float*          bqkv   = (float*)(w + 94371840);             //              18,432
  // attn partials: Opart (37.75MB) overlays dead Wtqkv+QKVbf; mlbuf overlays xbf
  __hip_bfloat16* Opart  = (__hip_bfloat16*)(w + 9437184);
  float*          mlbuf  = (float*)(w);

  // fused prep: x convert + bias concat + 4 weight transposes
  hipLaunchKernelGGL(prep_all, dim3(6930), dim3(256), 0, stream,
                     x, xbf, bq, bk, bv, bqkv, Wq, Wk, Wv, Wo, Wtqkv, Wot);

  // fused QKV GEMM: [3072,1536] @ [1536,4608] -> bf16, 128x64 tiles, BK=128
  hipLaunchKernelGGL((gemm_bt<__hip_bfloat16, 64>), dim3(NQKV / 64, S_LEN / 128),
                     dim3(256), 0, stream, xbf, Wtqkv, bqkv, QKVbf, S_LEN, NQKV, DMODEL);

  // fused mid: norm+rope (Q,K) + V transpose
  hipLaunchKernelGGL(mid_all, dim3(6720), dim3(256), 0, stream,
                     QKVbf, gq, gk, freqs, Qp, Kp, Vtb);

  // attention (balanced per-tg key-splits {2,3,4,3}; 864 equal blocks) + merge
  hipLaunchKernelGGL(attn_mfma, dim3(864), dim3(512), 0, stream,
                     Qp, Kp, Vtb, Opart, mlbuf);
  hipLaunchKernelGGL(attn_merge, dim3(S_LEN * NHEAD / 4), dim3(256), 0, stream,
                     Opart, mlbuf, AO);

  // output projection: 128x64 tiles, BK=128
  hipLaunchKernelGGL((gemm_bt<float, 64>), dim3(DMODEL / 64, S_LEN / 128),
                     dim3(256), 0, stream, AO, Wot, bo, out, S_LEN, DMODEL, DMODEL);
}

// Round 26
// 194.582 us; speedup vs baseline: 1.0289x; 1.0289x over previous
//
#include <hip/hip_runtime.h>
#include <hip/hip_bf16.h>
#include <math.h>

#define S_LEN 3072
#define DMODEL 1536
#define NQKV 4608
#define NHEAD 12
#define HDIM 128
#define NSPLIT 4   // max planes in Opart; per-tg split counts are {2,3,4,3}

typedef __attribute__((ext_vector_type(8))) short bf16x8;
typedef __attribute__((ext_vector_type(4))) float f32x4;
typedef __attribute__((ext_vector_type(4))) unsigned int u32x4;

__device__ __forceinline__ void gload_lds16(const void* g, void* lds) {
  __builtin_amdgcn_global_load_lds(
      (const __attribute__((address_space(1))) unsigned int*)g,
      (__attribute__((address_space(3))) unsigned int*)lds, 16, 0, 0);
}

// partitioned index p -> original sequence index s
__device__ __forceinline__ int invperm(int p) {
  int blk = p >> 7;
  int w   = p & 127;
  int fb  = blk / 6;
  int rem = blk - fb * 6;
  int hb  = rem / 3;
  int wb  = rem - hb * 3;
  int fi  = fb * 8 + (w >> 4);
  int hi  = hb * 4 + ((w >> 2) & 3);
  int wi  = wb * 4 + (w & 3);
  return (fi * 8 + hi) * 12 + wi;
}

// original sequence index s -> partitioned index p
__device__ __forceinline__ int fwdperm(int s) {
  int fi = s / 96;
  int rem = s - fi * 96;
  int hi = rem / 12;
  int wi = rem - hi * 12;
  int fb = fi >> 3, wf = fi & 7;
  int hb = hi >> 2, wh = hi & 3;
  int wb = wi >> 2, ww = wi & 3;
  return ((fb * 2 + hb) * 3 + wb) * 128 + wf * 16 + wh * 4 + ww;
}

__device__ __forceinline__ void store_out(float* p, float v) { *p = v; }
__device__ __forceinline__ void store_out(__hip_bfloat16* p, float v) { *p = __float2bfloat16(v); }

// ---------------------------------------------------------------------------
// Fused prep: blocks [0,4626): x fp32->bf16 convert + bias concat;
// blocks [4626,6930): the 4 weight transposes (fp32 -> bf16 transposed).
// ---------------------------------------------------------------------------
__global__ __launch_bounds__(256) void prep_all(
    const float* __restrict__ in, __hip_bfloat16* __restrict__ out,
    const float* __restrict__ bq, const float* __restrict__ bk,
    const float* __restrict__ bv, float* __restrict__ bqkv,
    const float* __restrict__ W0, const float* __restrict__ W1,
    const float* __restrict__ W2, const float* __restrict__ W3,
    __hip_bfloat16* __restrict__ Wtqkv, __hip_bfloat16* __restrict__ Wot)
{
  __shared__ __hip_bfloat16 Ls[64][67];
  const int bid = blockIdx.x, t = threadIdx.x;
  if (bid < 4608) {
    int i = bid * 256 + t;
    float4 v = ((const float4*)in)[i];
    __hip_bfloat16 b[4] = {__float2bfloat16(v.x), __float2bfloat16(v.y),
                           __float2bfloat16(v.z), __float2bfloat16(v.w)};
    ((ushort4*)out)[i] = *(ushort4*)b;
    return;
  }
  if (bid < 4626) {
    int j = (bid - 4608) * 256 + t;   // 0..4607
    float v = (j < 1536) ? bq[j] : (j < 3072) ? bk[j - 1536] : bv[j - 3072];
    bqkv[j] = v;
    return;
  }
  // weight transposes
  const int idx = bid - 4626;         // 0..2303
  const int z = idx / 576;
  const int rem = idx - z * 576;
  const int r0 = (rem / 24) * 64, c0 = (rem % 24) * 64;
  const float* W = (z == 0) ? W0 : (z == 1) ? W1 : (z == 2) ? W2 : W3;
  __hip_bfloat16* Wt = (z < 3) ? Wtqkv + (size_t)z * DMODEL * DMODEL : Wot;
  {
    int rr = t >> 2, cb = (t & 3) * 16;
    const float4* src = (const float4*)(W + (size_t)(r0 + rr) * DMODEL + c0 + cb);
    #pragma unroll
    for (int i = 0; i < 4; ++i) {
      float4 v = src[i];
      Ls[rr][cb + i * 4 + 0] = __float2bfloat16(v.x);
      Ls[rr][cb + i * 4 + 1] = __float2bfloat16(v.y);
      Ls[rr][cb + i * 4 + 2] = __float2bfloat16(v.z);
      Ls[rr][cb + i * 4 + 3] = __float2bfloat16(v.w);
    }
  }
  __syncthreads();
  {
    int cc = t >> 2, rb = (t & 3) * 16;
    unsigned short tmp[16];
    #pragma unroll
    for (int i = 0; i < 16; ++i) tmp[i] = *(unsigned short*)&Ls[rb + i][cc];
    uint4* dst = (uint4*)(Wt + (size_t)(c0 + cc) * DMODEL + r0 + rb);
    dst[0] = ((uint4*)tmp)[0];
    dst[1] = ((uint4*)tmp)[1];
  }
}

// ---------------------------------------------------------------------------
// bf16 MFMA GEMM, 128xBN tile, BK=64, single-buffered 24KB LDS, XOR-swizzled
// K-tiles (pre-swizzled global source + same XOR on reads), 2D XCD patch
// swizzle.  (R19/R24 structure -- measured best; BK=128 regressed in R25.)
// ---------------------------------------------------------------------------
template <typename OutT, int BN>
__global__ __launch_bounds__(256) void gemm_bt(
    const __hip_bfloat16* __restrict__ A, const __hip_bfloat16* __restrict__ Bt,
    const float* __restrict__ bias, OutT* __restrict__ C, int M, int N, int K)
{
  constexpr int NB = BN / 32;                 // B fragments per wave
  __shared__ __hip_bfloat16 As[128 * 64];
  __shared__ __hip_bfloat16 Bs[BN * 64];
  const int tid = threadIdx.x, lane = tid & 63, wid = tid >> 6;
  const int l15 = lane & 15, l4 = lane >> 4;
  // 2D XCD patch swizzle (bijective): xcd = lin&7 -> (col-chunk, row-chunk)
  const int lin = blockIdx.y * gridDim.x + blockIdx.x;
  const int xcd = lin & 7, idx = lin >> 3;
  const int CX = gridDim.x >> 2, CY = gridDim.y >> 1;
  const int cx = xcd & 3, cy = xcd >> 2;
  const int lc = idx % CX, lr = idx / CX;
  const int row0 = (cy * CY + lr) * 128, col0 = (cx * CX + lc) * BN;
  const int wr = (wid >> 1) * 64, wc = (wid & 1) * (BN / 2);

  f32x4 acc[4][NB] = {};
  const char* Ab = (const char*)A;
  const char* Bb = (const char*)Bt;

  auto STAGE = [&](int k0) {
    #pragma unroll
    for (int i = 0; i < 4; ++i) {
      int slot = i * 256 + tid;
      int r = slot >> 3;
      int b = ((slot & 7) * 16) ^ ((r & 7) << 4);   // pre-swizzled source
      gload_lds16(Ab + ((size_t)(row0 + r) * K + k0) * 2 + b,
                  (char*)As + slot * 16);
    }
    #pragma unroll
    for (int i = 0; i < BN / 32; ++i) {
      int slot = i * 256 + tid;
      int r = slot >> 3;
      int b = ((slot & 7) * 16) ^ ((r & 7) << 4);
      gload_lds16(Bb + ((size_t)(col0 + r) * K + k0) * 2 + b,
                  (char*)Bs + slot * 16);
    }
  };

  for (int k0 = 0; k0 < K; k0 += 64) {
    STAGE(k0);
    __syncthreads();              // vmcnt drain; staged tile visible
    #pragma unroll
    for (int kk = 0; kk < 2; ++kk) {
      bf16x8 a[4], b[NB];
      #pragma unroll
      for (int m = 0; m < 4; ++m) {
        int row = wr + m * 16 + l15;
        int byte = (kk * 64 + l4 * 16) ^ ((row & 7) << 4);
        a[m] = *(const bf16x8*)((const char*)As + row * 128 + byte);
      }
      #pragma unroll
      for (int n = 0; n < NB; ++n) {
        int row = wc + n * 16 + l15;
        int byte = (kk * 64 + l4 * 16) ^ ((row & 7) << 4);
        b[n] = *(const bf16x8*)((const char*)Bs + row * 128 + byte);
      }
      #pragma unroll
      for (int m = 0; m < 4; ++m)
        #pragma unroll
        for (int n = 0; n < NB; ++n)
          acc[m][n] = __builtin_amdgcn_mfma_f32_16x16x32_bf16(a[m], b[n], acc[m][n], 0, 0, 0);
    }
    __syncthreads();              // compute done -> safe to overwrite LDS
  }

  #pragma unroll
  for (int m = 0; m < 4; ++m) {
    #pragma unroll
    for (int r = 0; r < 4; ++r) {
      size_t row = row0 + wr + m * 16 + l4 * 4 + r;
      #pragma unroll
      for (int n = 0; n < NB; ++n) {
        int col = col0 + wc + n * 16 + l15;
        store_out(&C[row * N + col], acc[m][n][r] + bias[col]);
      }
    }
  }
}

// ---------------------------------------------------------------------------
// Fused mid: blocks [0,6144): RMSNorm+RoPE for Q (bid&1==0) / K (bid&1==1),
// permuted head-blocked bf16 out (Q pre-scaled into log2 domain);
// blocks [6144,6720): V -> transposed+permuted Vt[h][d][p].
// ---------------------------------------------------------------------------
__global__ __launch_bounds__(256) void mid_all(
    const __hip_bfloat16* __restrict__ X,
    const float* __restrict__ gq, const float* __restrict__ gk,
    const float* __restrict__ freqs,
    __hip_bfloat16* __restrict__ OutQ, __hip_bfloat16* __restrict__ OutK,
    __hip_bfloat16* __restrict__ Vt)
{
  __shared__ __hip_bfloat16 Ls[64][136];
  __shared__ float wsum[4];
  const int bid = blockIdx.x, tid = threadIdx.x;
  if (bid < 6144) {
    const int s = bid >> 1, sec = bid & 1;
    const float* g = sec ? gk : gq;
    __hip_bfloat16* Out = sec ? OutK : OutQ;
    const float qsc = sec ? 1.0f : (0.08838834764831843f * 1.4426950408889634f);
    const unsigned int* row = (const unsigned int*)(X + (size_t)s * NQKV + sec * 1536);
    float e0[3], e1[3];
    float ss = 0.f;
    #pragma unroll
    for (int i = 0; i < 3; ++i) {
      unsigned int u = row[tid + i * 256];
      float a = __uint_as_float(u << 16);
      float b = __uint_as_float(u & 0xffff0000u);
      e0[i] = a; e1[i] = b;
      ss += a * a + b * b;
    }
    #pragma unroll
    for (int off = 32; off > 0; off >>= 1) ss += __shfl_down(ss, off, 64);
    if ((tid & 63) == 0) wsum[tid >> 6] = ss;
    __syncthreads();
    float rs = rsqrtf((wsum[0] + wsum[1] + wsum[2] + wsum[3]) * (1.f / DMODEL) + 1e-5f);
    rs *= qsc;
    const int p = fwdperm(s);
    #pragma unroll
    for (int i = 0; i < 3; ++i) {
      int pi = tid + i * 256;             // pair index 0..767
      int n = pi >> 6, d2 = pi & 63;
      float c  = freqs[(size_t)s * 128 + 2 * d2];
      float sn = freqs[(size_t)s * 128 + 2 * d2 + 1];
      float y0 = e0[i] * rs * g[2 * pi];
      float y1 = e1[i] * rs * g[2 * pi + 1];
      float o0 = y0 * c - y1 * sn;
      float o1 = y0 * sn + y1 * c;
      __hip_bfloat16 b0 = __float2bfloat16(o0), b1 = __float2bfloat16(o1);
      unsigned int u = ((unsigned int)(*(unsigned short*)&b1) << 16) | (*(unsigned short*)&b0);
      ((unsigned int*)Out)[(((size_t)n * S_LEN + p) * HDIM + 2 * d2) >> 1] = u;
    }
    return;
  }
  // V transpose: idx 0..575 -> (p0, h)
  const int idx = bid - 6144;
  const int p0 = (idx % 48) * 64, h = idx / 48;
  const __hip_bfloat16* Vsec = X + 3072;    // V section of QKVbf
  {
    int pl = tid & 63, dg = tid >> 6;
    int sidx = invperm(p0 + pl);
    const uint4* src = (const uint4*)(Vsec + (size_t)sidx * NQKV + h * HDIM + dg * 32);
    #pragma unroll
    for (int i = 0; i < 4; ++i) {
      uint4 v = src[i];
      *(uint4*)&Ls[pl][dg * 32 + i * 8] = v;
    }
  }
  __syncthreads();
  {
    int d = tid >> 1, ph = tid & 1;
    unsigned short tmp[32];
    #pragma unroll
    for (int i = 0; i < 32; ++i) tmp[i] = *(unsigned short*)&Ls[ph * 32 + i][d];
    uint4* dst = (uint4*)(Vt + ((size_t)h * HDIM + d) * S_LEN + p0 + ph * 32);
    #pragma unroll
    for (int i = 0; i < 4; ++i) dst[i] = ((uint4*)tmp)[i];
  }
}

// ---------------------------------------------------------------------------
// MFMA flash attention (R23: swapped QK^T, register-resident P, sigma
// K-swizzle, balanced per-tg key-splits {2,3,4,3}, setprio, hoisted LDS
// bases, T4 double-buffer with counted vmcnt + raw s_barrier).
// ---------------------------------------------------------------------------
__global__ __launch_bounds__(512) void attn_mfma(
    const __hip_bfloat16* __restrict__ Qp, const __hip_bfloat16* __restrict__ Kp,
    const __hip_bfloat16* __restrict__ Vt,
    __hip_bfloat16* __restrict__ Opart, float* __restrict__ ml)
{
  __shared__ __hip_bfloat16 Ks[2][64 * 128];              // [key][d], sigma-swizzled
  __shared__ __hip_bfloat16 Vs[2][64 * 128];              // [d][key], swizzled

  // ---- XCD-locality remap: 864 blocks, 108 per XCD ----
  const int hw = blockIdx.x;                 // 0..863
  const int L  = (hw & 7) * 108 + (hw >> 3);
  const int j  = L % 6;
  const int c  = (L / 6) % 12;               // (tg,split) combo
  const int h  = L / 72;
  int tg, split;
  if (c < 2)      { tg = 0; split = c; }
  else if (c < 5) { tg = 1; split = c - 2; }
  else if (c < 9) { tg = 2; split = c - 5; }
  else            { tg = 3; split = c - 9; }
  const int qb = tg * 6 + j;

  const int tid = threadIdx.x, lane = tid & 63, wid = tid >> 6;
  const int l15 = lane & 15, l4 = lane >> 4;

  const int cbegin = split * 12, cend = cbegin + 12;   // 12 chunks per block

  const char* Kh = (const char*)(Kp + (size_t)h * S_LEN * HDIM);
  const char* Vh = (const char*)(Vt + (size_t)h * HDIM * S_LEN);

  // gathered key row base for QK^T A-operand
  const int kbase = 8 * (l15 >> 2) + (l15 & 3);
  // sigma(key)<<4 is ct-independent: sigma = (l15&3) | (((l15>>2)&1)<<2)
  const int ksw = (((l15 & 3) | (((l15 >> 2) & 1) << 2))) << 4;

  // loop-invariant LDS read base pointers (buffer 0; buffer 1 = +16384 B)
  const char* kbp[4];
  #pragma unroll
  for (int dc = 0; dc < 4; ++dc)
    kbp[dc] = (const char*)Ks[0] + kbase * 256 + ((dc * 64 + l4 * 16) ^ ksw);
  const char* vbp[2];
  #pragma unroll
  for (int ks = 0; ks < 2; ++ks)
    vbp[ks] = (const char*)Vs[0] + l15 * 128 + ((ks * 64 + l4 * 16) ^ ((l15 & 7) << 4));

  // hoisted 32-bit staging offsets (K uses sigma; V uses (row&7))
  unsigned int koffA, voffA;
  {
    unsigned int kr = tid >> 4;
    unsigned int sig = (kr & 3) | (((kr >> 3) & 1) << 2);
    koffA = kr * 256 + (((tid & 15) * 16) ^ (sig << 4));
    unsigned int vr = tid >> 3;
    voffA = vr * (S_LEN * 2) + (((tid & 7) * 16) ^ ((vr & 7) << 4));
  }

  auto k0_of = [&](int ci) { return ci * 64 + ((tg == 3 && ci >= 12) ? 768 : 0); };
  auto STAGE = [&](int buf, int k0) {
    const char* ks = Kh + (size_t)k0 * 256;
    char* kd = (char*)Ks[buf];
    gload_lds16(ks + koffA,        kd + tid * 16);
    gload_lds16(ks + koffA + 8192, kd + tid * 16 + 8192);   // row+32: sigma invariant
    const char* vs = Vh + (size_t)k0 * 2 + voffA;
    char* vd = (char*)Vs[buf];
    gload_lds16(vs,                          vd + tid * 16);
    gload_lds16(vs + (size_t)64 * S_LEN * 2, vd + tid * 16 + 8192);
  };

  // Q fragments in registers (pre-scaled; serve as MFMA B-operand)
  bf16x8 aq[4];
  {
    const __hip_bfloat16* qr = Qp + (size_t)h * S_LEN * HDIM
        + (size_t)(qb * 128 + wid * 16 + l15) * HDIM + l4 * 8;
    #pragma unroll
    for (int dc = 0; dc < 4; ++dc) aq[dc] = *(const bf16x8*)(qr + dc * 32);
  }

  f32x4 oacc[8] = {};
  float m2 = -1e30f;     // running max for this lane's q (=l15)
  float lsum = 0.f;      // per-lane partial (its 16 keys per chunk)

  // prologue: stage first chunk into buffer 0
  STAGE(0, k0_of(cbegin));
  int cur = 0;

  for (int ci = cbegin; ci < cend; ++ci) {
    if (ci + 1 < cend) {
      STAGE(cur ^ 1, k0_of(ci + 1));
      // wait only cur's 4 loads (issued last iteration / prologue);
      // the 4 just-issued prefetch loads stay in flight across the barrier
      asm volatile("s_waitcnt vmcnt(4)" ::: "memory");
    } else {
      asm volatile("s_waitcnt vmcnt(0)" ::: "memory");
    }
    __builtin_amdgcn_s_barrier();     // cur's staged K/V visible to all waves
    __builtin_amdgcn_sched_barrier(0);

    const int bufoff = cur << 14;     // byte offset to current buffer

    // swapped QK^T: sfr[ct] = S^T for gathered keys, q = l15
    f32x4 sfr[4] = {};
    __builtin_amdgcn_s_setprio(1);
    #pragma unroll
    for (int ct = 0; ct < 4; ++ct) {
      const int cto = ((ct >> 1) * 32 + (ct & 1) * 4) * 256;   // 0,1024,8192,9216
      #pragma unroll
      for (int dc = 0; dc < 4; ++dc) {
        bf16x8 kf = *(const bf16x8*)(kbp[dc] + bufoff + cto);
        sfr[ct] = __builtin_amdgcn_mfma_f32_16x16x32_bf16(kf, aq[dc], sfr[ct], 0, 0, 0);
      }
    }
    __builtin_amdgcn_s_setprio(0);
    // defer-max online softmax (per-lane partial max over 16 values)
    float lmax = fmaxf(
        fmaxf(fmaxf(sfr[0][0], sfr[0][1]), fmaxf(sfr[0][2], sfr[0][3])),
        fmaxf(fmaxf(fmaxf(sfr[1][0], sfr[1][1]), fmaxf(sfr[1][2], sfr[1][3])),
              fmaxf(fmaxf(fmaxf(sfr[2][0], sfr[2][1]), fmaxf(sfr[2][2], sfr[2][3])),
                    fmaxf(fmaxf(sfr[3][0], sfr[3][1]), fmaxf(sfr[3][2], sfr[3][3])))));
    bool grow = lmax > m2 + 8.f;
    if (ci == cbegin || __any(grow)) {
      float mf = lmax;
      mf = fmaxf(mf, __shfl_xor(mf, 16, 64));
      mf = fmaxf(mf, __shfl_xor(mf, 32, 64));
      float mn = fmaxf(m2, mf);
      float corr = exp2f(m2 - mn);
      m2 = mn;
      lsum *= corr;
      float cr[4];
      #pragma unroll
      for (int r = 0; r < 4; ++r) cr[r] = __shfl(corr, l4 * 4 + r, 64);
      #pragma unroll
      for (int n = 0; n < 8; ++n)
        #pragma unroll
        for (int r = 0; r < 4; ++r) oacc[n][r] *= cr[r];
    }
    // P = exp2(S - m) in place; accumulate per-lane row-sum partial
    #pragma unroll
    for (int ct = 0; ct < 4; ++ct)
      #pragma unroll
      for (int r = 0; r < 4; ++r) {
        float p = exp2f(sfr[ct][r] - m2);
        sfr[ct][r] = p;
        lsum += p;
      }
    // PV: A = P packed lane-locally (no LDS), B = V via base+immediate reads
    #pragma unroll
    for (int ks = 0; ks < 2; ++ks) {
      u32x4 wv;
      {
        __hip_bfloat16 a0 = __float2bfloat16(sfr[2 * ks][0]);
        __hip_bfloat16 a1 = __float2bfloat16(sfr[2 * ks][1]);
        __hip_bfloat16 a2 = __float2bfloat16(sfr[2 * ks][2]);
        __hip_bfloat16 a3 = __float2bfloat16(sfr[2 * ks][3]);
        __hip_bfloat16 b0 = __float2bfloat16(sfr[2 * ks + 1][0]);
        __hip_bfloat16 b1 = __float2bfloat16(sfr[2 * ks + 1][1]);
        __hip_bfloat16 b2 = __float2bfloat16(sfr[2 * ks + 1][2]);
        __hip_bfloat16 b3 = __float2bfloat16(sfr[2 * ks + 1][3]);
        wv[0] = ((unsigned int)(*(unsigned short*)&a1) << 16) | (*(unsigned short*)&a0);
        wv[1] = ((unsigned int)(*(unsigned short*)&a3) << 16) | (*(unsigned short*)&a2);
        wv[2] = ((unsigned int)(*(unsigned short*)&b1) << 16) | (*(unsigned short*)&b0);
        wv[3] = ((unsigned int)(*(unsigned short*)&b3) << 16) | (*(unsigned short*)&b2);
      }
      bf16x8 pa = __builtin_bit_cast(bf16x8, wv);
      __builtin_amdgcn_s_setprio(1);
      #pragma unroll
      for (int n = 0; n < 8; ++n) {
        bf16x8 bv = *(const bf16x8*)(vbp[ks] + bufoff + n * 2048);
        oacc[n] = __builtin_amdgcn_mfma_f32_16x16x32_bf16(pa, bv, oacc[n], 0, 0, 0);
      }
      __builtin_amdgcn_s_setprio(0);
    }
    __builtin_amdgcn_sched_barrier(0);
    __builtin_amdgcn_s_barrier();   // all waves done reading cur -> reusable
    cur ^= 1;
  }

  // epilogue: full row-sum per q (=l15) via 2 shuffles; normalize & write
  float t = lsum;
  t += __shfl_xor(t, 16, 64);
  t += __shfl_xor(t, 32, 64);
  float inv = 1.0f / t;
  #pragma unroll
  for (int r = 0; r < 4; ++r) {
    float invr = __shfl(inv, l4 * 4 + r, 64);   // lane (l4*4+r) owns that q
    int qrow = qb * 128 + wid * 16 + l4 * 4 + r;
    size_t rowid = (size_t)(split * NHEAD + h) * S_LEN + qrow;
    __hip_bfloat16* dst = Opart + rowid * HDIM;
    #pragma unroll
    for (int n = 0; n < 8; ++n)
      dst[n * 16 + l15] = __float2bfloat16(oacc[n][r] * invr);
  }
  if (lane < 16) {
    int qrow = qb * 128 + wid * 16 + lane;
    size_t rowid = (size_t)(split * NHEAD + h) * S_LEN + qrow;
    ml[rowid * 2 + 0] = m2;
    ml[rowid * 2 + 1] = t;
  }
}

// ---------------------------------------------------------------------------
// Merge the key-split partials, fully unrolled over NSPLIT=4 with invalid
// planes masked (m=-1e30 -> weight exp2(-inf)*l=0; max unaffected).
// Per-tg valid plane counts: {2,3,4,3}.
// ---------------------------------------------------------------------------
__global__ __launch_bounds__(256) void attn_merge(
    const __hip_bfloat16* __restrict__ Opart, const float* __restrict__ ml,
    __hip_bfloat16* __restrict__ AO)
{
  const int rid = blockIdx.x * 4 + (threadIdx.x >> 6);
  const int lane = threadIdx.x & 63;
  const int h = rid / S_LEN, q = rid - h * S_LEN;
  const int tg = q / 768;
  const int nsp = (tg == 0) ? 2 : (tg == 2) ? 4 : 3;
  size_t rr[NSPLIT];
  float m[NSPLIT], l[NSPLIT];
  float mm = -1e30f;
  #pragma unroll
  for (int s = 0; s < NSPLIT; ++s) {
    rr[s] = (size_t)(s * NHEAD + h) * S_LEN + q;
    bool valid = (s < nsp);
    m[s] = valid ? ml[rr[s] * 2] : -1e30f;
    l[s] = valid ? ml[rr[s] * 2 + 1] : 0.f;
    mm = fmaxf(mm, m[s]);
  }
  float wsum = 0.f, wgt[NSPLIT];
  #pragma unroll
  for (int s = 0; s < NSPLIT; ++s) { wgt[s] = l[s] * exp2f(m[s] - mm); wsum += wgt[s]; }
  float inv = 1.0f / wsum;
  float o0 = 0.f, o1 = 0.f;
  #pragma unroll
  for (int s = 0; s < NSPLIT; ++s) {
    unsigned int u = ((const unsigned int*)(Opart + rr[s] * HDIM))[lane];
    float a = wgt[s] * inv;
    o0 += a * __uint_as_float(u << 16);
    o1 += a * __uint_as_float(u & 0xffff0000u);
  }
  __hip_bfloat16 b0 = __float2bfloat16(o0), b1 = __float2bfloat16(o1);
  unsigned int u = ((unsigned int)(*(unsigned short*)&b1) << 16) | (*(unsigned short*)&b0);
  int sorig = invperm(q);
  ((unsigned int*)(AO + (size_t)sorig * DMODEL + h * HDIM))[lane] = u;
}

// ---------------------------------------------------------------------------
extern "C" void kernel_launch(void* const* d_in, const int* in_sizes, int n_in,
                              void* d_out, int out_size, void* d_ws, size_t ws_size,
                              hipStream_t stream)
{
  (void)in_sizes; (void)n_in; (void)out_size; (void)ws_size;
  const float* x     = (const float*)d_in[0];
  const float* freqs = (const float*)d_in[1];
  const float* Wq    = (const float*)d_in[2];
  const float* bq    = (const float*)d_in[3];
  const float* Wk    = (const float*)d_in[4];
  const float* bk    = (const float*)d_in[5];
  const float* Wv    = (const float*)d_in[6];
  const float* bv    = (const float*)d_in[7];
  const float* Wo    = (const float*)d_in[8];
  const float* bo    = (const float*)d_in[9];
  const float* gq    = (const float*)d_in[10];
  const float* gk    = (const float*)d_in[11];
  float* out = (float*)d_out;

  // ws layout (Wot after AO so Opart can overlay Wtqkv+QKVbf):
  char* w = (char*)d_ws;
  __hip_bfloat16* xbf    = (__hip_bfloat16*)(w);               //  0        9,437,184
  __hip_bfloat16* Wtqkv  = (__hip_bfloat16*)(w + 9437184);     //          14,155,776
  __hip_bfloat16* QKVbf  = (__hip_bfloat16*)(w + 23592960);    //          28,311,552
  __hip_bfloat16* Qp     = (__hip_bfloat16*)(w + 51904512);    //           9,437,184
  __hip_bfloat16* Kp     = (__hip_bfloat16*)(w + 61341696);    //           9,437,184
  __hip_bfloat16* Vtb    = (__hip_bfloat16*)(w + 70778880);    //           9,437,184
  __hip_bfloat16* AO     = (__hip_bfloat16*)(w + 80216064);    //           9,437,184
  __hip_bfloat16* Wot    = (__hip_bfloat16*)(w + 89653248);    //           4,718,592
  float*          bqkv   = (float*)(w + 94371840);             //              18,432
  // attn partials: Opart (37.75MB) overlays dead Wtqkv+QKVbf; mlbuf overlays xbf
  __hip_bfloat16* Opart  = (__hip_bfloat16*)(w + 9437184);
  float*          mlbuf  = (float*)(w);

  // fused prep: x convert + bias concat + 4 weight transposes
  hipLaunchKernelGGL(prep_all, dim3(6930), dim3(256), 0, stream,
                     x, xbf, bq, bk, bv, bqkv, Wq, Wk, Wv, Wo, Wtqkv, Wot);

  // fused QKV GEMM: [3072,1536] @ [1536,4608] -> bf16, 128x64 tiles, BK=64
  hipLaunchKernelGGL((gemm_bt<__hip_bfloat16, 64>), dim3(NQKV / 64, S_LEN / 128),
                     dim3(256), 0, stream, xbf, Wtqkv, bqkv, QKVbf, S_LEN, NQKV, DMODEL);

  // fused mid: norm+rope (Q,K) + V transpose
  hipLaunchKernelGGL(mid_all, dim3(6720), dim3(256), 0, stream,
                     QKVbf, gq, gk, freqs, Qp, Kp, Vtb);

  // attention (balanced per-tg key-splits {2,3,4,3}; 864 equal blocks) + merge
  hipLaunchKernelGGL(attn_mfma, dim3(864), dim3(512), 0, stream,
                     Qp, Kp, Vtb, Opart, mlbuf);
  hipLaunchKernelGGL(attn_merge, dim3(S_LEN * NHEAD / 4), dim3(256), 0, stream,
                     Opart, mlbuf, AO);

  // output projection: 128x64 tiles, BK=64
  hipLaunchKernelGGL((gemm_bt<float, 64>), dim3(DMODEL / 64, S_LEN / 128),
                     dim3(256), 0, stream, AO, Wot, bo, out, S_LEN, DMODEL, DMODEL);
}